// Round 13
// baseline (333.894 us; speedup 1.0000x reference)
//
#include <hip/hip_runtime.h>
#include <hip/hip_fp16.h>
#include <math.h>

#define FF 256
#define HH 64

typedef __attribute__((ext_vector_type(8))) short short8;
typedef __attribute__((ext_vector_type(4))) float f32x4;
typedef unsigned long long ull;

// cheap gelu: A&S 7.1.26 erf approximation, |err| <= 1.5e-7
__device__ __forceinline__ float gelu_f(float x) {
    float ax = fabsf(x) * 0.70710678118654752f;
    float t = __builtin_amdgcn_rcpf(fmaf(0.3275911f, ax, 1.0f));
    float poly = t * fmaf(t, fmaf(t, fmaf(t, fmaf(t, 1.061405429f, -1.453152027f),
                  1.421413741f), -0.284496736f), 0.254829592f);
    float er = 1.0f - poly * __expf(-ax * ax);
    er = (x < 0.f) ? -er : er;
    return 0.5f * x * (1.0f + er);
}

__device__ __forceinline__ unsigned short bf16rne(float f) {
    unsigned u = __float_as_uint(f);
    unsigned r = u + 0x7FFFu + ((u >> 16) & 1u);
    return (unsigned short)(r >> 16);
}

// split f into bf16 hi + bf16 lo (RNE)
__device__ __forceinline__ void bf16split(float f, short& hi, short& lo) {
    unsigned u = __float_as_uint(f);
    unsigned r = u + 0x7FFFu + ((u >> 16) & 1u);
    hi = (short)(r >> 16);
    float fh = __uint_as_float(r & 0xFFFF0000u);
    float fl = f - fh;
    unsigned u2 = __float_as_uint(fl);
    unsigned r2 = u2 + 0x7FFFu + ((u2 >> 16) & 1u);
    lo = (short)(r2 >> 16);
}

__device__ __forceinline__ __half2 shfl_xor_h2(__half2 v, int off) {
    union { __half2 h; int i; } u;
    u.h = v;
    u.i = __shfl_xor(u.i, off, 64);
    return u.h;
}

// ---- W fragment tables in workspace (bf16 hi/lo, fragment-ordered) ----
__global__ __launch_bounds__(256) void k_wprep(
        const float* __restrict__ Wp,
        const float* __restrict__ Wq1, const float* __restrict__ Wk1, const float* __restrict__ Wv1,
        const float* __restrict__ Wq2, const float* __restrict__ Wk2, const float* __restrict__ Wv2,
        short* __restrict__ wf) {
    int total = 16384 + 6 * 4096;
    for (int gid = blockIdx.x * 256 + threadIdx.x; gid < total; gid += gridDim.x * 256) {
        const float* W;
        int fid, hibase, lobase;
        if (gid < 16384) {
            W = Wp; fid = gid; hibase = 0; lobase = 16384;
        } else {
            int t = gid - 16384;
            int m = t >> 12;
            fid = t & 4095;
            switch (m) {
                case 0: W = Wq1; break;
                case 1: W = Wk1; break;
                case 2: W = Wv1; break;
                case 3: W = Wq2; break;
                case 4: W = Wk2; break;
                default: W = Wv2; break;
            }
            hibase = 32768 + m * 8192;
            lobase = hibase + 4096;
        }
        int j    = fid & 7;
        int lane = (fid >> 3) & 63;
        int ct   = (fid >> 9) & 3;
        int s    = fid >> 11;
        int k    = s * 32 + (lane >> 4) * 8 + j;
        int col  = ct * 16 + (lane & 15);
        short hi, lo;
        bf16split(W[k * HH + col], hi, lo);
        wf[hibase + fid] = hi;
        wf[lobase + fid] = lo;
    }
}

// ================= radix-partition CSR build v2 (no global atomics) =================
// bucket = dst >> 9 (512 nodes/bucket). pack = (local<<38)|(src<<21)|eid (47 bits).

// Pass A: per-block bucket histogram -> blockHist[bucket*PB + block]
__global__ __launch_bounds__(256) void k_partA(const int* __restrict__ dst,
        int* __restrict__ blockHist, int E, int PB, int NB) {
    __shared__ int hist[256];
    int t = threadIdx.x, bid = blockIdx.x;
    hist[t] = 0;
    __syncthreads();
    int base = bid * 4096;
    int e0 = base + t * 4;
    if (base + 4095 < E) {
        #pragma unroll
        for (int i = 0; i < 4; ++i) {
            int4 d = *reinterpret_cast<const int4*>(dst + e0 + i * 1024);
            atomicAdd(&hist[d.x >> 9], 1);
            atomicAdd(&hist[d.y >> 9], 1);
            atomicAdd(&hist[d.z >> 9], 1);
            atomicAdd(&hist[d.w >> 9], 1);
        }
    } else {
        for (int i = 0; i < 4; ++i)
            for (int j = 0; j < 4; ++j) {
                int e = e0 + i * 1024 + j;
                if (e < E) atomicAdd(&hist[dst[e] >> 9], 1);
            }
    }
    __syncthreads();
    if (t < NB) blockHist[t * PB + bid] = hist[t];
}

// Pass A2: per-bucket exclusive scan over blocks (in place); total -> bucketTotal
__global__ __launch_bounds__(512) void k_partA2(int* __restrict__ blockHist,
        int* __restrict__ bucketTotal, int PB) {
    __shared__ int buf[512];
    int t = threadIdx.x, b = blockIdx.x;
    int orig = (t < PB) ? blockHist[b * PB + t] : 0;
    buf[t] = orig;
    __syncthreads();
    #pragma unroll
    for (int off = 1; off < 512; off <<= 1) {
        int v = (t >= off) ? buf[t - off] : 0;
        __syncthreads();
        buf[t] += v;
        __syncthreads();
    }
    if (t < PB) blockHist[b * PB + t] = buf[t] - orig;
    if (t == 511) bucketTotal[b] = buf[511];
}

// Pass A2b: scan bucket totals -> bucketBase[NB+1]; also rowptr[N] = E
__global__ __launch_bounds__(256) void k_partA2b(const int* __restrict__ bucketTotal,
        int* __restrict__ bucketBase, int* __restrict__ rowptr, int NB, int N, int E) {
    __shared__ int buf[256];
    int t = threadIdx.x;
    int orig = (t < NB) ? bucketTotal[t] : 0;
    buf[t] = orig;
    __syncthreads();
    #pragma unroll
    for (int off = 1; off < 256; off <<= 1) {
        int v = (t >= off) ? buf[t - off] : 0;
        __syncthreads();
        buf[t] += v;
        __syncthreads();
    }
    if (t < NB) bucketBase[t] = buf[t] - orig;
    if (t == 0) { bucketBase[NB] = buf[255]; rowptr[N] = E; }
}

// Pass B3: scatter packed edges into bucket-partitioned bps64 (one 8B store/edge).
__device__ __forceinline__ void do_partB3(int bid, const int* __restrict__ src,
        const int* __restrict__ dst, const int* __restrict__ blockBase,
        const int* __restrict__ bucketBase,
        ull* __restrict__ bps, int E, int PB, int NB) {
    if (bid >= PB) return;
    __shared__ int cur[256];
    int t = threadIdx.x;
    if (t < NB) cur[t] = bucketBase[t] + blockBase[t * PB + bid];
    __syncthreads();
    int base = bid * 4096;
    int e0 = base + t * 4;
    auto place = [&](int d, int s, int e) {
        int bu = d >> 9;
        int pos = atomicAdd(&cur[bu], 1);
        bps[pos] = ((ull)(d & 511) << 38) | ((ull)s << 21) | (unsigned)e;
    };
    if (base + 4095 < E) {
        #pragma unroll
        for (int i = 0; i < 4; ++i) {
            int4 d4 = *reinterpret_cast<const int4*>(dst + e0 + i * 1024);
            int4 s4 = *reinterpret_cast<const int4*>(src + e0 + i * 1024);
            int eb = e0 + i * 1024;
            place(d4.x, s4.x, eb);
            place(d4.y, s4.y, eb + 1);
            place(d4.z, s4.z, eb + 2);
            place(d4.w, s4.w, eb + 3);
        }
    } else {
        for (int i = 0; i < 4; ++i)
            for (int j = 0; j < 4; ++j) {
                int e = e0 + i * 1024 + j;
                if (e < E) place(dst[e], src[e], e);
            }
    }
}

// Pass C1: per-bucket CSR finalize. Writes rowptr, esrc (bucket-local), posArr (coalesced).
__device__ __forceinline__ void do_partC1(int b, const ull* __restrict__ bps,
        const int* __restrict__ bucketBase,
        int* __restrict__ rowptr, int* __restrict__ esrc, int* __restrict__ posArr,
        int N, int NB) {
    if (b >= NB) return;
    __shared__ int cnt[512], sc[512], cur[512], pairbuf[256];
    int t = threadIdx.x;
    cnt[t] = 0; cnt[t + 256] = 0;
    cur[t] = 0; cur[t + 256] = 0;
    __syncthreads();
    int rB = bucketBase[b], rE = bucketBase[b + 1];
    for (int p = rB + t; p < rE; p += 256)
        atomicAdd(&cnt[(int)(bps[p] >> 38)], 1);
    __syncthreads();
    int a  = cnt[2 * t], b2 = cnt[2 * t + 1];
    int ps = a + b2;
    pairbuf[t] = ps;
    __syncthreads();
    #pragma unroll
    for (int off = 1; off < 256; off <<= 1) {
        int v = (t >= off) ? pairbuf[t - off] : 0;
        __syncthreads();
        pairbuf[t] += v;
        __syncthreads();
    }
    int pex = pairbuf[t] - ps;
    sc[2 * t]     = pex;
    sc[2 * t + 1] = pex + a;
    __syncthreads();
    int lo = b << 9;
    #pragma unroll
    for (int i = 0; i < 2; ++i) {
        int idx = t + i * 256;
        int node = lo + idx;
        if (node < N) rowptr[node] = rB + sc[idx];
    }
    for (int p = rB + t; p < rE; p += 256) {
        ull u = bps[p];
        int local = (int)(u >> 38);
        int s = (int)((u >> 21) & 0x1FFFF);
        int r = atomicAdd(&cur[local], 1);
        int pos = rB + sc[local] + r;
        esrc[pos] = s;
        posArr[p] = pos;
    }
}

// Pass C2: inv[eid] = pos (the single random scatter; fused under edge1)
__device__ __forceinline__ void do_partC2(int bid, const ull* __restrict__ bps,
        const int* __restrict__ posArr, int* __restrict__ inv, int E) {
    int p0 = (bid * 256 + threadIdx.x) * 4;
    if (p0 + 3 < E) {
        ull u0 = bps[p0], u1 = bps[p0 + 1], u2 = bps[p0 + 2], u3 = bps[p0 + 3];
        int4 ps = *reinterpret_cast<const int4*>(posArr + p0);
        inv[(int)(u0 & 0x1FFFFF)] = ps.x;
        inv[(int)(u1 & 0x1FFFFF)] = ps.y;
        inv[(int)(u2 & 0x1FFFFF)] = ps.z;
        inv[(int)(u3 & 0x1FFFFF)] = ps.w;
    } else {
        for (int p = p0; p < E; ++p)
            inv[(int)(bps[p] & 0x1FFFFF)] = posArr[p];
    }
}

__device__ __forceinline__ void do_attn(int bid, const float* __restrict__ ecsr,
        const int* __restrict__ inv, float* __restrict__ attn, int E) {
    int e0 = (bid * 256 + threadIdx.x) * 4;
    if (e0 + 3 < E) {
        int4 i4 = *reinterpret_cast<const int4*>(inv + e0);
        float4 a;
        a.x = ecsr[i4.x]; a.y = ecsr[i4.y]; a.z = ecsr[i4.z]; a.w = ecsr[i4.w];
        *reinterpret_cast<float4*>(attn + e0) = a;
    } else {
        for (int e = e0; e < E; ++e) attn[e] = ecsr[inv[e]];
    }
}

__device__ __forceinline__ void do_proj(int bid, const float* __restrict__ x,
        const short* __restrict__ wf, const float* __restrict__ b,
        float* __restrict__ h, int n) {
    if (bid * 64 >= n) return;
    int lane = threadIdx.x & 63;
    int w    = threadIdx.x >> 6;
    int m    = lane & 15, g = lane >> 4;
    int rowc = min(bid * 64 + w * 16 + m, n - 1);
    const float* xrow = x + (size_t)rowc * FF + g * 8;
    const short* wlo = wf + 16384;
    f32x4 acc[4];
    #pragma unroll
    for (int ct = 0; ct < 4; ++ct) acc[ct] = (f32x4){0.f, 0.f, 0.f, 0.f};
    #pragma unroll
    for (int s = 0; s < 8; ++s) {
        float4 a0 = *reinterpret_cast<const float4*>(xrow + s * 32);
        float4 a1 = *reinterpret_cast<const float4*>(xrow + s * 32 + 4);
        float av[8] = {a0.x, a0.y, a0.z, a0.w, a1.x, a1.y, a1.z, a1.w};
        short8 ah, al;
        #pragma unroll
        for (int j = 0; j < 8; ++j) { short hi, lo; bf16split(av[j], hi, lo); ah[j] = hi; al[j] = lo; }
        #pragma unroll
        for (int ct = 0; ct < 4; ++ct) {
            int fo = ((s * 4 + ct) * 64 + lane) * 8;
            short8 bh = *reinterpret_cast<const short8*>(wf + fo);
            short8 bl = *reinterpret_cast<const short8*>(wlo + fo);
            acc[ct] = __builtin_amdgcn_mfma_f32_16x16x32_bf16(ah, bh, acc[ct], 0, 0, 0);
            acc[ct] = __builtin_amdgcn_mfma_f32_16x16x32_bf16(al, bh, acc[ct], 0, 0, 0);
            acc[ct] = __builtin_amdgcn_mfma_f32_16x16x32_bf16(ah, bl, acc[ct], 0, 0, 0);
        }
    }
    int orow0 = bid * 64 + w * 16 + g * 4;
    #pragma unroll
    for (int ct = 0; ct < 4; ++ct) {
        int col = ct * 16 + m;
        float bias = b[col];
        #pragma unroll
        for (int r = 0; r < 4; ++r) {
            int row = orow0 + r;
            if (row < n) h[(size_t)row * HH + col] = acc[ct][r] + bias;   // raw; gelu in qkv
        }
    }
}

// kv row layout (128 halves): block b=c>>3 : k[c] at b*16+(c&7), v[c] at b*16+8+(c&7)
__device__ __forceinline__ void do_qkv(int bid, const float* __restrict__ hsrc,
        const short* __restrict__ wfq, const short* __restrict__ wfk, const short* __restrict__ wfv,
        __half* __restrict__ qh, __half* __restrict__ kv, int n) {
    if (bid * 64 >= n) return;
    int lane = threadIdx.x & 63;
    int w    = threadIdx.x >> 6;
    int m    = lane & 15, g = lane >> 4;
    int rowc = min(bid * 64 + w * 16 + m, n - 1);
    const float* hrow = hsrc + (size_t)rowc * HH + g * 8;
    f32x4 aq[4], ak[4], av_[4];
    #pragma unroll
    for (int ct = 0; ct < 4; ++ct) {
        aq[ct] = (f32x4){0.f, 0.f, 0.f, 0.f};
        ak[ct] = (f32x4){0.f, 0.f, 0.f, 0.f};
        av_[ct] = (f32x4){0.f, 0.f, 0.f, 0.f};
    }
    #pragma unroll
    for (int s = 0; s < 2; ++s) {
        float4 a0 = *reinterpret_cast<const float4*>(hrow + s * 32);
        float4 a1 = *reinterpret_cast<const float4*>(hrow + s * 32 + 4);
        float avv[8] = {a0.x, a0.y, a0.z, a0.w, a1.x, a1.y, a1.z, a1.w};
        short8 ah;
        #pragma unroll
        for (int j = 0; j < 8; ++j) ah[j] = (short)bf16rne(gelu_f(avv[j]));
        #pragma unroll
        for (int ct = 0; ct < 4; ++ct) {
            int fo = ((s * 4 + ct) * 64 + lane) * 8;
            short8 qh8 = *reinterpret_cast<const short8*>(wfq + fo);
            short8 ql8 = *reinterpret_cast<const short8*>(wfq + 4096 + fo);
            short8 kh8 = *reinterpret_cast<const short8*>(wfk + fo);
            short8 kl8 = *reinterpret_cast<const short8*>(wfk + 4096 + fo);
            short8 vh8 = *reinterpret_cast<const short8*>(wfv + fo);
            short8 vl8 = *reinterpret_cast<const short8*>(wfv + 4096 + fo);
            aq[ct] = __builtin_amdgcn_mfma_f32_16x16x32_bf16(ah, qh8, aq[ct], 0, 0, 0);
            aq[ct] = __builtin_amdgcn_mfma_f32_16x16x32_bf16(ah, ql8, aq[ct], 0, 0, 0);
            ak[ct] = __builtin_amdgcn_mfma_f32_16x16x32_bf16(ah, kh8, ak[ct], 0, 0, 0);
            ak[ct] = __builtin_amdgcn_mfma_f32_16x16x32_bf16(ah, kl8, ak[ct], 0, 0, 0);
            av_[ct] = __builtin_amdgcn_mfma_f32_16x16x32_bf16(ah, vh8, av_[ct], 0, 0, 0);
            av_[ct] = __builtin_amdgcn_mfma_f32_16x16x32_bf16(ah, vl8, av_[ct], 0, 0, 0);
        }
    }
    int orow0 = bid * 64 + w * 16 + g * 4;
    #pragma unroll
    for (int ct = 0; ct < 4; ++ct) {
        int col = ct * 16 + m;
        int cb  = (col >> 3) * 16 + (col & 7);
        #pragma unroll
        for (int r = 0; r < 4; ++r) {
            int row = orow0 + r;
            if (row < n) {
                qh[(size_t)row * HH + col]     = __float2half(aq[ct][r]);
                kv[(size_t)row * 128 + cb]     = __float2half(ak[ct][r]);
                kv[(size_t)row * 128 + cb + 8] = __float2half(av_[ct][r]);
            }
        }
    }
}

// ---------------- edge phase body: one wave/node, 8 lanes/edge, f16 packed math ----
template<bool LAST>
__device__ __forceinline__ void do_edge(int ebid,
        const __half* __restrict__ qarr, const __half* __restrict__ kv,
        const int* __restrict__ rowptr,
        const int* __restrict__ esrc,
        float* __restrict__ ecsr,
        float* __restrict__ hout,
        float* __restrict__ signals,
        const float* __restrict__ Wsig, const float* __restrict__ bsig,
        int n) {
    int node = ebid * 4 + (threadIdx.x >> 6);
    if (node >= n) return;
    int lane = threadIdx.x & 63;
    int li = lane & 7, g = lane >> 3;
    int start = rowptr[node], end = rowptr[node + 1];
    int deg = end - start;
    __half2 q2[4];
    {
        union { uint4 u; __half2 h[4]; } Q;
        Q.u = *reinterpret_cast<const uint4*>(qarr + (size_t)node * HH + li * 8);
        #pragma unroll
        for (int j = 0; j < 4; ++j) q2[j] = Q.h[j];
    }
    int p0 = start + lane;
    int el = (p0 < end) ? esrc[p0] : 0;   // first 64 source indices in registers

    __half2 acc2[4];
    #pragma unroll
    for (int j = 0; j < 4; ++j) acc2[j] = __float2half2_rn(0.f);
    float s = 0.f;
    for (int c = 0; c < deg; c += 16) {
        int idx0 = c + g, idx1 = c + 8 + g;
        bool v0 = idx0 < deg, v1 = idx1 < deg;
        int sv0, sv1;
        if (c + 16 <= 64) {
            sv0 = __shfl(el, idx0);
            sv1 = __shfl(el, idx1);
        } else {
            sv0 = v0 ? esrc[start + idx0] : 0;
            sv1 = v1 ? esrc[start + idx1] : 0;
        }
        const __half* b0 = kv + (size_t)sv0 * 128 + li * 16;
        const __half* b1 = kv + (size_t)sv1 * 128 + li * 16;
        union { uint4 u; __half2 h[4]; } K0, V0, K1, V1;
        K0.u = *reinterpret_cast<const uint4*>(b0);
        V0.u = *reinterpret_cast<const uint4*>(b0 + 8);
        K1.u = *reinterpret_cast<const uint4*>(b1);
        V1.u = *reinterpret_cast<const uint4*>(b1 + 8);
        __half2 d20 = __float2half2_rn(0.f);
        __half2 d21 = __float2half2_rn(0.f);
        #pragma unroll
        for (int j = 0; j < 4; ++j) {
            d20 = __hfma2(q2[j], K0.h[j], d20);
            d21 = __hfma2(q2[j], K1.h[j], d21);
        }
        float d0 = __low2float(d20) + __high2float(d20);
        float d1 = __low2float(d21) + __high2float(d21);
        d0 += __shfl_xor(d0, 1); d1 += __shfl_xor(d1, 1);
        d0 += __shfl_xor(d0, 2); d1 += __shfl_xor(d1, 2);
        d0 += __shfl_xor(d0, 4); d1 += __shfl_xor(d1, 4);
        float e0 = v0 ? __expf(fmaxf(d0 * 0.125f, 0.f)) : 0.f;
        float e1 = v1 ? __expf(fmaxf(d1 * 0.125f, 0.f)) : 0.f;
        s += e0 + e1;
        if (v0 && li == 0) ecsr[start + idx0] = e0;
        if (v1 && li == 0) ecsr[start + idx1] = e1;
        __half2 e20 = __float2half2_rn(e0);
        __half2 e21 = __float2half2_rn(e1);
        #pragma unroll
        for (int j = 0; j < 4; ++j) {
            acc2[j] = __hfma2(e20, V0.h[j], acc2[j]);
            acc2[j] = __hfma2(e21, V1.h[j], acc2[j]);
        }
    }
    // combine the 8 groups
    #pragma unroll
    for (int off = 8; off < 64; off <<= 1) {
        s += __shfl_xor(s, off);
        #pragma unroll
        for (int j = 0; j < 4; ++j)
            acc2[j] = __hadd2(acc2[j], shfl_xor_h2(acc2[j], off));
    }
    float inv = 1.0f / (s + 1e-16f);
    float af[8];
    #pragma unroll
    for (int j = 0; j < 4; ++j) {
        af[2 * j]     = __low2float(acc2[j]);
        af[2 * j + 1] = __high2float(acc2[j]);
    }

    if (!LAST) {
        if (g == 0) {
            float4 o0, o1;
            o0.x = af[0] * inv; o0.y = af[1] * inv; o0.z = af[2] * inv; o0.w = af[3] * inv;
            o1.x = af[4] * inv; o1.y = af[5] * inv; o1.z = af[6] * inv; o1.w = af[7] * inv;
            *reinterpret_cast<float4*>(hout + (size_t)node * HH + li * 8)     = o0;
            *reinterpret_cast<float4*>(hout + (size_t)node * HH + li * 8 + 4) = o1;
        }
    } else {
        float4 w0 = *reinterpret_cast<const float4*>(Wsig + li * 8);
        float4 w1 = *reinterpret_cast<const float4*>(Wsig + li * 8 + 4);
        float t = af[0] * w0.x + af[1] * w0.y + af[2] * w0.z + af[3] * w0.w
                + af[4] * w1.x + af[5] * w1.y + af[6] * w1.z + af[7] * w1.w;
        t *= inv;
        t += __shfl_xor(t, 1);
        t += __shfl_xor(t, 2);
        t += __shfl_xor(t, 4);
        if (lane == 0) signals[node] = t + bsig[0];
    }
    // normalize in place (coalesced)
    for (int p = p0; p < end; p += 64)
        ecsr[p] *= inv;
}

// ---------------- fused dispatches (parity-interleaved block split) ----------------
__global__ __launch_bounds__(256) void k_proj_partB3(
        const float* __restrict__ x, const short* __restrict__ wf,
        const float* __restrict__ b, float* __restrict__ h, int n,
        const int* __restrict__ src, const int* __restrict__ dst,
        const int* __restrict__ blockBase, const int* __restrict__ bucketBase,
        ull* __restrict__ bps, int E, int PB, int NB) {
    int bid = blockIdx.x >> 1;
    if ((blockIdx.x & 1) == 0) do_proj(bid, x, wf, b, h, n);
    else                       do_partB3(bid, src, dst, blockBase, bucketBase, bps, E, PB, NB);
}

__global__ __launch_bounds__(256) void k_qkv_partC1(
        const float* __restrict__ hsrc,
        const short* __restrict__ wfq, const short* __restrict__ wfk, const short* __restrict__ wfv,
        __half* __restrict__ qh, __half* __restrict__ kv, int n,
        const ull* __restrict__ bps, const int* __restrict__ bucketBase,
        int* __restrict__ rowptr, int* __restrict__ esrc, int* __restrict__ posArr, int NB) {
    int bid = blockIdx.x >> 1;
    if ((blockIdx.x & 1) == 0) do_qkv(bid, hsrc, wfq, wfk, wfv, qh, kv, n);
    else                       do_partC1(bid, bps, bucketBase, rowptr, esrc, posArr, n, NB);
}

__global__ __launch_bounds__(256) void k_edge1_partC2(
        const __half* __restrict__ qarr, const __half* __restrict__ kv,
        const int* __restrict__ rowptr, const int* __restrict__ esrc,
        float* __restrict__ ecsr, float* __restrict__ hout, int n,
        const ull* __restrict__ bps, const int* __restrict__ posArr,
        int* __restrict__ inv, int E, int C2B) {
    int bid = blockIdx.x >> 1;
    if ((blockIdx.x & 1) == 0)
        do_edge<false>(bid, qarr, kv, rowptr, esrc, ecsr, hout, nullptr, nullptr, nullptr, n);
    else if (bid < C2B)
        do_partC2(bid, bps, posArr, inv, E);
}

__global__ __launch_bounds__(256) void k_qkv_attn(
        const float* __restrict__ hsrc,
        const short* __restrict__ wfq, const short* __restrict__ wfk, const short* __restrict__ wfv,
        __half* __restrict__ qh, __half* __restrict__ kv, int n,
        const float* __restrict__ ecsr, const int* __restrict__ inv,
        float* __restrict__ attn, int E) {
    int bid = blockIdx.x >> 1;
    if ((blockIdx.x & 1) == 0) do_qkv(bid, hsrc, wfq, wfk, wfv, qh, kv, n);
    else                       do_attn(bid, ecsr, inv, attn, E);
}

__global__ __launch_bounds__(256) void k_edge2(
        const __half* __restrict__ qarr, const __half* __restrict__ kv,
        const int* __restrict__ rowptr, const int* __restrict__ esrc,
        float* __restrict__ ecsr, float* __restrict__ signals,
        const float* __restrict__ Wsig, const float* __restrict__ bsig, int n) {
    do_edge<true>(blockIdx.x, qarr, kv, rowptr, esrc, ecsr, nullptr, signals, Wsig, bsig, n);
}

__global__ __launch_bounds__(256) void k_attn(const float* __restrict__ ecsr,
        const int* __restrict__ inv, float* __restrict__ attn, int E) {
    do_attn(blockIdx.x, ecsr, inv, attn, E);
}

extern "C" void kernel_launch(void* const* d_in, const int* in_sizes, int n_in,
                              void* d_out, int out_size, void* d_ws, size_t ws_size,
                              hipStream_t stream) {
    const float* x   = (const float*)d_in[0];
    const int*   ei  = (const int*)  d_in[1];
    const float* Wp  = (const float*)d_in[2];
    const float* bp  = (const float*)d_in[3];
    const float* Wq1 = (const float*)d_in[4];
    const float* Wk1 = (const float*)d_in[5];
    const float* Wv1 = (const float*)d_in[6];
    const float* Wq2 = (const float*)d_in[7];
    const float* Wk2 = (const float*)d_in[8];
    const float* Wv2 = (const float*)d_in[9];
    const float* Wsg = (const float*)d_in[10];
    const float* bsg = (const float*)d_in[11];

    const int N = in_sizes[0] / FF;
    const int E = in_sizes[1] / 2;
    const int* src = ei;
    const int* dst = ei + E;

    const int NB = (N + 511) >> 9;       // buckets of 512 nodes (needs NB <= 256)
    const int PB = (E + 4095) >> 12;     // partition blocks of 4096 edges (needs PB <= 512)

    char* ws = (char*)d_ws;
    size_t off = 0;
    auto alloc = [&](size_t bytes) -> void* {
        void* p = ws + off;
        off += (bytes + 255) & ~(size_t)255;
        return p;
    };
    __half* qh   = (__half*)alloc((size_t)N * HH * 2);
    __half* kv   = (__half*)alloc((size_t)N * 128 * 2);
    float* h     = (float*)alloc((size_t)N * HH * 4);
    float* ecsr  = (float*)alloc((size_t)E * 4);
    int* inv     = (int*)alloc((size_t)E * 4);
    int* esrc    = (int*)alloc((size_t)E * 4);
    int* posArr  = (int*)alloc((size_t)E * 4);
    ull* bps     = (ull*)alloc((size_t)E * 8);
    int* rowptr  = (int*)alloc((size_t)(N + 1) * 4);
    int* blockHist   = (int*)alloc((size_t)NB * PB * 4);
    int* bucketTotal = (int*)alloc((size_t)NB * 4);
    int* bucketBase  = (int*)alloc((size_t)(NB + 1) * 4);
    short* wf    = (short*)alloc((size_t)81920 * 2);  // W fragment tables

    float* out     = (float*)d_out;
    float* signals = out;
    float* attn1   = out + N;
    float* attn2   = out + N + E;

    // W fragment prep (independent of everything else)
    k_wprep<<<64, 256, 0, stream>>>(Wp, Wq1, Wk1, Wv1, Wq2, Wk2, Wv2, wf);

    // partition prefix sums
    k_partA<<<PB, 256, 0, stream>>>(dst, blockHist, E, PB, NB);
    k_partA2<<<NB, 512, 0, stream>>>(blockHist, bucketTotal, PB);
    k_partA2b<<<1, 256, 0, stream>>>(bucketTotal, bucketBase, rowptr, NB, N, E);

    int gemmBlocks = (N + 63) / 64;              // 1563
    int e4Blocks   = ((E + 3) / 4 + 255) / 256;  // 1563
    int edgeBlocks = (N + 3) / 4;                // 25000

    // proj (MFMA) ∥ partB3 (one 8B store per edge)
    int f1 = 2 * max(gemmBlocks, PB);
    k_proj_partB3<<<f1, 256, 0, stream>>>(x, wf, bp, h, N,
            src, dst, blockHist, bucketBase, bps, E, PB, NB);

    const short* wfbase = wf + 32768;
    // qkv1 (MFMA) ∥ partC1 (per-bucket finalize)
    int f2 = 2 * max(gemmBlocks, NB);
    k_qkv_partC1<<<f2, 256, 0, stream>>>(h, wfbase, wfbase + 8192, wfbase + 16384,
            qh, kv, N, bps, bucketBase, rowptr, esrc, posArr, NB);

    // edge1 ∥ partC2 (inv scatter hidden under the long edge phase)
    int f3 = 2 * max(edgeBlocks, e4Blocks);
    k_edge1_partC2<<<f3, 256, 0, stream>>>(qh, kv, rowptr, esrc, ecsr, h, N,
            bps, posArr, inv, E, e4Blocks);

    // qkv2 (MFMA) ∥ attn1 (gather)
    int f4 = 2 * max(gemmBlocks, e4Blocks);
    k_qkv_attn<<<f4, 256, 0, stream>>>(h, wfbase + 24576, wfbase + 32768, wfbase + 40960,
            qh, kv, N, ecsr, inv, attn1, E);

    // edge2 (+ fused signal head)
    k_edge2<<<edgeBlocks, 256, 0, stream>>>(qh, kv, rowptr, esrc, ecsr,
            signals, Wsg, bsg, N);
    k_attn<<<e4Blocks, 256, 0, stream>>>(ecsr, inv, attn2, E);
}

// Round 14
// 307.772 us; speedup vs baseline: 1.0849x; 1.0849x over previous
//
#include <hip/hip_runtime.h>
#include <hip/hip_fp16.h>
#include <math.h>

#define FF 256
#define HH 64

typedef __attribute__((ext_vector_type(8))) short short8;
typedef __attribute__((ext_vector_type(4))) float f32x4;
typedef unsigned long long ull;

// cheap gelu: A&S 7.1.26 erf approximation, |err| <= 1.5e-7
__device__ __forceinline__ float gelu_f(float x) {
    float ax = fabsf(x) * 0.70710678118654752f;
    float t = __builtin_amdgcn_rcpf(fmaf(0.3275911f, ax, 1.0f));
    float poly = t * fmaf(t, fmaf(t, fmaf(t, fmaf(t, 1.061405429f, -1.453152027f),
                  1.421413741f), -0.284496736f), 0.254829592f);
    float er = 1.0f - poly * __expf(-ax * ax);
    er = (x < 0.f) ? -er : er;
    return 0.5f * x * (1.0f + er);
}

__device__ __forceinline__ unsigned short bf16rne(float f) {
    unsigned u = __float_as_uint(f);
    unsigned r = u + 0x7FFFu + ((u >> 16) & 1u);
    return (unsigned short)(r >> 16);
}

// split f into bf16 hi + bf16 lo (RNE)
__device__ __forceinline__ void bf16split(float f, short& hi, short& lo) {
    unsigned u = __float_as_uint(f);
    unsigned r = u + 0x7FFFu + ((u >> 16) & 1u);
    hi = (short)(r >> 16);
    float fh = __uint_as_float(r & 0xFFFF0000u);
    float fl = f - fh;
    unsigned u2 = __float_as_uint(fl);
    unsigned r2 = u2 + 0x7FFFu + ((u2 >> 16) & 1u);
    lo = (short)(r2 >> 16);
}

__device__ __forceinline__ __half2 shfl_xor_h2(__half2 v, int off) {
    union { __half2 h; int i; } u;
    u.h = v;
    u.i = __shfl_xor(u.i, off, 64);
    return u.h;
}

// ---- W fragment tables in workspace (bf16 hi/lo, fragment-ordered) ----
__global__ __launch_bounds__(256) void k_wprep(
        const float* __restrict__ Wp,
        const float* __restrict__ Wq1, const float* __restrict__ Wk1, const float* __restrict__ Wv1,
        const float* __restrict__ Wq2, const float* __restrict__ Wk2, const float* __restrict__ Wv2,
        short* __restrict__ wf) {
    int total = 16384 + 6 * 4096;
    for (int gid = blockIdx.x * 256 + threadIdx.x; gid < total; gid += gridDim.x * 256) {
        const float* W;
        int fid, hibase, lobase;
        if (gid < 16384) {
            W = Wp; fid = gid; hibase = 0; lobase = 16384;
        } else {
            int t = gid - 16384;
            int m = t >> 12;
            fid = t & 4095;
            switch (m) {
                case 0: W = Wq1; break;
                case 1: W = Wk1; break;
                case 2: W = Wv1; break;
                case 3: W = Wq2; break;
                case 4: W = Wk2; break;
                default: W = Wv2; break;
            }
            hibase = 32768 + m * 8192;
            lobase = hibase + 4096;
        }
        int j    = fid & 7;
        int lane = (fid >> 3) & 63;
        int ct   = (fid >> 9) & 3;
        int s    = fid >> 11;
        int k    = s * 32 + (lane >> 4) * 8 + j;
        int col  = ct * 16 + (lane & 15);
        short hi, lo;
        bf16split(W[k * HH + col], hi, lo);
        wf[hibase + fid] = hi;
        wf[lobase + fid] = lo;
    }
}

// ================= radix-partition CSR build v3 (no global atomics) =================
// bucket = dst >> 9 (512 nodes/bucket). pack = (local<<38)|(src<<21)|eid (47 bits).

// Pass A: per-block bucket histogram -> blockHist[bucket*PB + block]
__global__ __launch_bounds__(256) void k_partA(const int* __restrict__ dst,
        int* __restrict__ blockHist, int E, int PB, int NB) {
    __shared__ int hist[256];
    int t = threadIdx.x, bid = blockIdx.x;
    hist[t] = 0;
    __syncthreads();
    int base = bid * 4096;
    int e0 = base + t * 4;
    if (base + 4095 < E) {
        #pragma unroll
        for (int i = 0; i < 4; ++i) {
            int4 d = *reinterpret_cast<const int4*>(dst + e0 + i * 1024);
            atomicAdd(&hist[d.x >> 9], 1);
            atomicAdd(&hist[d.y >> 9], 1);
            atomicAdd(&hist[d.z >> 9], 1);
            atomicAdd(&hist[d.w >> 9], 1);
        }
    } else {
        for (int i = 0; i < 4; ++i)
            for (int j = 0; j < 4; ++j) {
                int e = e0 + i * 1024 + j;
                if (e < E) atomicAdd(&hist[dst[e] >> 9], 1);
            }
    }
    __syncthreads();
    if (t < NB) blockHist[t * PB + bid] = hist[t];
}

// Pass A2: per-bucket exclusive scan over blocks (in place); total -> bucketTotal
__global__ __launch_bounds__(512) void k_partA2(int* __restrict__ blockHist,
        int* __restrict__ bucketTotal, int PB) {
    __shared__ int buf[512];
    int t = threadIdx.x, b = blockIdx.x;
    int orig = (t < PB) ? blockHist[b * PB + t] : 0;
    buf[t] = orig;
    __syncthreads();
    #pragma unroll
    for (int off = 1; off < 512; off <<= 1) {
        int v = (t >= off) ? buf[t - off] : 0;
        __syncthreads();
        buf[t] += v;
        __syncthreads();
    }
    if (t < PB) blockHist[b * PB + t] = buf[t] - orig;
    if (t == 511) bucketTotal[b] = buf[511];
}

// Pass A2b: scan bucket totals -> bucketBase[NB+1]; also rowptr[N] = E
__global__ __launch_bounds__(256) void k_partA2b(const int* __restrict__ bucketTotal,
        int* __restrict__ bucketBase, int* __restrict__ rowptr, int NB, int N, int E) {
    __shared__ int buf[256];
    int t = threadIdx.x;
    int orig = (t < NB) ? bucketTotal[t] : 0;
    buf[t] = orig;
    __syncthreads();
    #pragma unroll
    for (int off = 1; off < 256; off <<= 1) {
        int v = (t >= off) ? buf[t - off] : 0;
        __syncthreads();
        buf[t] += v;
        __syncthreads();
    }
    if (t < NB) bucketBase[t] = buf[t] - orig;
    if (t == 0) { bucketBase[NB] = buf[255]; rowptr[N] = E; }
}

// Pass B3: scatter packed edges into bucket-partitioned bps64 (one 8B store/edge).
__device__ __forceinline__ void do_partB3(int bid, const int* __restrict__ src,
        const int* __restrict__ dst, const int* __restrict__ blockBase,
        const int* __restrict__ bucketBase,
        ull* __restrict__ bps, int E, int PB, int NB) {
    if (bid >= PB) return;
    __shared__ int cur[256];
    int t = threadIdx.x;
    if (t < NB) cur[t] = bucketBase[t] + blockBase[t * PB + bid];
    __syncthreads();
    int base = bid * 4096;
    int e0 = base + t * 4;
    auto place = [&](int d, int s, int e) {
        int bu = d >> 9;
        int pos = atomicAdd(&cur[bu], 1);
        bps[pos] = ((ull)(d & 511) << 38) | ((ull)s << 21) | (unsigned)e;
    };
    if (base + 4095 < E) {
        #pragma unroll
        for (int i = 0; i < 4; ++i) {
            int4 d4 = *reinterpret_cast<const int4*>(dst + e0 + i * 1024);
            int4 s4 = *reinterpret_cast<const int4*>(src + e0 + i * 1024);
            int eb = e0 + i * 1024;
            place(d4.x, s4.x, eb);
            place(d4.y, s4.y, eb + 1);
            place(d4.z, s4.z, eb + 2);
            place(d4.w, s4.w, eb + 3);
        }
    } else {
        for (int i = 0; i < 4; ++i)
            for (int j = 0; j < 4; ++j) {
                int e = e0 + i * 1024 + j;
                if (e < E) place(dst[e], src[e], e);
            }
    }
}

// Pass C1: per-bucket CSR finalize. Writes rowptr, esrc (bucket-local), inv (scatter).
__device__ __forceinline__ void do_partC1(int b, const ull* __restrict__ bps,
        const int* __restrict__ bucketBase,
        int* __restrict__ rowptr, int* __restrict__ esrc, int* __restrict__ inv,
        int N, int NB) {
    if (b >= NB) return;
    __shared__ int cnt[512], sc[512], cur[512], pairbuf[256];
    int t = threadIdx.x;
    cnt[t] = 0; cnt[t + 256] = 0;
    cur[t] = 0; cur[t + 256] = 0;
    __syncthreads();
    int rB = bucketBase[b], rE = bucketBase[b + 1];
    for (int p = rB + t; p < rE; p += 256)
        atomicAdd(&cnt[(int)(bps[p] >> 38)], 1);
    __syncthreads();
    int a  = cnt[2 * t], b2 = cnt[2 * t + 1];
    int ps = a + b2;
    pairbuf[t] = ps;
    __syncthreads();
    #pragma unroll
    for (int off = 1; off < 256; off <<= 1) {
        int v = (t >= off) ? pairbuf[t - off] : 0;
        __syncthreads();
        pairbuf[t] += v;
        __syncthreads();
    }
    int pex = pairbuf[t] - ps;
    sc[2 * t]     = pex;
    sc[2 * t + 1] = pex + a;
    __syncthreads();
    int lo = b << 9;
    #pragma unroll
    for (int i = 0; i < 2; ++i) {
        int idx = t + i * 256;
        int node = lo + idx;
        if (node < N) rowptr[node] = rB + sc[idx];
    }
    for (int p = rB + t; p < rE; p += 256) {
        ull u = bps[p];
        int local = (int)(u >> 38);
        int s = (int)((u >> 21) & 0x1FFFF);
        int r = atomicAdd(&cur[local], 1);
        int pos = rB + sc[local] + r;
        esrc[pos] = s;
        inv[(int)(u & 0x1FFFFF)] = pos;
    }
}

// edge-order attention: attn[e] = ecsr_unnorm[inv[e]] * dnode[dst[e]]
__device__ __forceinline__ void do_attn(int bid, const float* __restrict__ ecsr,
        const int* __restrict__ inv, const float* __restrict__ dnode,
        const int* __restrict__ dst, float* __restrict__ attn, int E) {
    int e0 = (bid * 256 + threadIdx.x) * 4;
    if (e0 + 3 < E) {
        int4 i4 = *reinterpret_cast<const int4*>(inv + e0);
        int4 d4 = *reinterpret_cast<const int4*>(dst + e0);
        float4 a;
        a.x = ecsr[i4.x] * dnode[d4.x];
        a.y = ecsr[i4.y] * dnode[d4.y];
        a.z = ecsr[i4.z] * dnode[d4.z];
        a.w = ecsr[i4.w] * dnode[d4.w];
        *reinterpret_cast<float4*>(attn + e0) = a;
    } else {
        for (int e = e0; e < E; ++e) attn[e] = ecsr[inv[e]] * dnode[dst[e]];
    }
}

__device__ __forceinline__ void do_proj(int bid, const float* __restrict__ x,
        const short* __restrict__ wf, const float* __restrict__ b,
        float* __restrict__ h, int n) {
    if (bid * 64 >= n) return;
    int lane = threadIdx.x & 63;
    int w    = threadIdx.x >> 6;
    int m    = lane & 15, g = lane >> 4;
    int rowc = min(bid * 64 + w * 16 + m, n - 1);
    const float* xrow = x + (size_t)rowc * FF + g * 8;
    const short* wlo = wf + 16384;
    f32x4 acc[4];
    #pragma unroll
    for (int ct = 0; ct < 4; ++ct) acc[ct] = (f32x4){0.f, 0.f, 0.f, 0.f};
    #pragma unroll
    for (int s = 0; s < 8; ++s) {
        float4 a0 = *reinterpret_cast<const float4*>(xrow + s * 32);
        float4 a1 = *reinterpret_cast<const float4*>(xrow + s * 32 + 4);
        float av[8] = {a0.x, a0.y, a0.z, a0.w, a1.x, a1.y, a1.z, a1.w};
        short8 ah, al;
        #pragma unroll
        for (int j = 0; j < 8; ++j) { short hi, lo; bf16split(av[j], hi, lo); ah[j] = hi; al[j] = lo; }
        #pragma unroll
        for (int ct = 0; ct < 4; ++ct) {
            int fo = ((s * 4 + ct) * 64 + lane) * 8;
            short8 bh = *reinterpret_cast<const short8*>(wf + fo);
            short8 bl = *reinterpret_cast<const short8*>(wlo + fo);
            acc[ct] = __builtin_amdgcn_mfma_f32_16x16x32_bf16(ah, bh, acc[ct], 0, 0, 0);
            acc[ct] = __builtin_amdgcn_mfma_f32_16x16x32_bf16(al, bh, acc[ct], 0, 0, 0);
            acc[ct] = __builtin_amdgcn_mfma_f32_16x16x32_bf16(ah, bl, acc[ct], 0, 0, 0);
        }
    }
    int orow0 = bid * 64 + w * 16 + g * 4;
    #pragma unroll
    for (int ct = 0; ct < 4; ++ct) {
        int col = ct * 16 + m;
        float bias = b[col];
        #pragma unroll
        for (int r = 0; r < 4; ++r) {
            int row = orow0 + r;
            if (row < n) h[(size_t)row * HH + col] = acc[ct][r] + bias;   // raw; gelu in qkv
        }
    }
}

// kv row layout (128 halves): block b=c>>3 : k[c] at b*16+(c&7), v[c] at b*16+8+(c&7)
__device__ __forceinline__ void do_qkv(int bid, const float* __restrict__ hsrc,
        const short* __restrict__ wfq, const short* __restrict__ wfk, const short* __restrict__ wfv,
        __half* __restrict__ qh, __half* __restrict__ kv, int n) {
    if (bid * 64 >= n) return;
    int lane = threadIdx.x & 63;
    int w    = threadIdx.x >> 6;
    int m    = lane & 15, g = lane >> 4;
    int rowc = min(bid * 64 + w * 16 + m, n - 1);
    const float* hrow = hsrc + (size_t)rowc * HH + g * 8;
    f32x4 aq[4], ak[4], av_[4];
    #pragma unroll
    for (int ct = 0; ct < 4; ++ct) {
        aq[ct] = (f32x4){0.f, 0.f, 0.f, 0.f};
        ak[ct] = (f32x4){0.f, 0.f, 0.f, 0.f};
        av_[ct] = (f32x4){0.f, 0.f, 0.f, 0.f};
    }
    #pragma unroll
    for (int s = 0; s < 2; ++s) {
        float4 a0 = *reinterpret_cast<const float4*>(hrow + s * 32);
        float4 a1 = *reinterpret_cast<const float4*>(hrow + s * 32 + 4);
        float avv[8] = {a0.x, a0.y, a0.z, a0.w, a1.x, a1.y, a1.z, a1.w};
        short8 ah;
        #pragma unroll
        for (int j = 0; j < 8; ++j) ah[j] = (short)bf16rne(gelu_f(avv[j]));
        #pragma unroll
        for (int ct = 0; ct < 4; ++ct) {
            int fo = ((s * 4 + ct) * 64 + lane) * 8;
            short8 qh8 = *reinterpret_cast<const short8*>(wfq + fo);
            short8 ql8 = *reinterpret_cast<const short8*>(wfq + 4096 + fo);
            short8 kh8 = *reinterpret_cast<const short8*>(wfk + fo);
            short8 kl8 = *reinterpret_cast<const short8*>(wfk + 4096 + fo);
            short8 vh8 = *reinterpret_cast<const short8*>(wfv + fo);
            short8 vl8 = *reinterpret_cast<const short8*>(wfv + 4096 + fo);
            aq[ct] = __builtin_amdgcn_mfma_f32_16x16x32_bf16(ah, qh8, aq[ct], 0, 0, 0);
            aq[ct] = __builtin_amdgcn_mfma_f32_16x16x32_bf16(ah, ql8, aq[ct], 0, 0, 0);
            ak[ct] = __builtin_amdgcn_mfma_f32_16x16x32_bf16(ah, kh8, ak[ct], 0, 0, 0);
            ak[ct] = __builtin_amdgcn_mfma_f32_16x16x32_bf16(ah, kl8, ak[ct], 0, 0, 0);
            av_[ct] = __builtin_amdgcn_mfma_f32_16x16x32_bf16(ah, vh8, av_[ct], 0, 0, 0);
            av_[ct] = __builtin_amdgcn_mfma_f32_16x16x32_bf16(ah, vl8, av_[ct], 0, 0, 0);
        }
    }
    int orow0 = bid * 64 + w * 16 + g * 4;
    #pragma unroll
    for (int ct = 0; ct < 4; ++ct) {
        int col = ct * 16 + m;
        int cb  = (col >> 3) * 16 + (col & 7);
        #pragma unroll
        for (int r = 0; r < 4; ++r) {
            int row = orow0 + r;
            if (row < n) {
                qh[(size_t)row * HH + col]     = __float2half(aq[ct][r]);
                kv[(size_t)row * 128 + cb]     = __float2half(ak[ct][r]);
                kv[(size_t)row * 128 + cb + 8] = __float2half(av_[ct][r]);
            }
        }
    }
}

// ---------------- edge phase: one wave/node, 8 lanes/edge; unnormalized ecsr + dnode --
template<bool LAST>
__global__ __launch_bounds__(256) void k_edge(
        const __half* __restrict__ qarr, const __half* __restrict__ kv,
        const int* __restrict__ rowptr,
        const int* __restrict__ esrc,
        float* __restrict__ ecsr,
        float* __restrict__ dnode,
        float* __restrict__ hout,
        float* __restrict__ signals,
        const float* __restrict__ Wsig, const float* __restrict__ bsig,
        int n) {
    int node = blockIdx.x * 4 + (threadIdx.x >> 6);
    if (node >= n) return;
    int lane = threadIdx.x & 63;
    int li = lane & 7, g = lane >> 3;
    int start = rowptr[node], end = rowptr[node + 1];
    int deg = end - start;
    __half2 q2[4];
    {
        union { uint4 u; __half2 h[4]; } Q;
        Q.u = *reinterpret_cast<const uint4*>(qarr + (size_t)node * HH + li * 8);
        #pragma unroll
        for (int j = 0; j < 4; ++j) q2[j] = Q.h[j];
    }
    int p0 = start + lane;
    int el = (p0 < end) ? esrc[p0] : 0;   // first 64 source indices in registers

    __half2 acc2[4];
    #pragma unroll
    for (int j = 0; j < 4; ++j) acc2[j] = __float2half2_rn(0.f);
    float s = 0.f;
    for (int c = 0; c < deg; c += 16) {
        int idx0 = c + g, idx1 = c + 8 + g;
        bool v0 = idx0 < deg, v1 = idx1 < deg;
        int sv0, sv1;
        if (c + 16 <= 64) {
            sv0 = __shfl(el, idx0);
            sv1 = __shfl(el, idx1);
        } else {
            sv0 = v0 ? esrc[start + idx0] : 0;
            sv1 = v1 ? esrc[start + idx1] : 0;
        }
        const __half* b0 = kv + (size_t)sv0 * 128 + li * 16;
        const __half* b1 = kv + (size_t)sv1 * 128 + li * 16;
        union { uint4 u; __half2 h[4]; } K0, V0, K1, V1;
        K0.u = *reinterpret_cast<const uint4*>(b0);
        V0.u = *reinterpret_cast<const uint4*>(b0 + 8);
        K1.u = *reinterpret_cast<const uint4*>(b1);
        V1.u = *reinterpret_cast<const uint4*>(b1 + 8);
        __half2 d20 = __float2half2_rn(0.f);
        __half2 d21 = __float2half2_rn(0.f);
        #pragma unroll
        for (int j = 0; j < 4; ++j) {
            d20 = __hfma2(q2[j], K0.h[j], d20);
            d21 = __hfma2(q2[j], K1.h[j], d21);
        }
        float d0 = __low2float(d20) + __high2float(d20);
        float d1 = __low2float(d21) + __high2float(d21);
        d0 += __shfl_xor(d0, 1); d1 += __shfl_xor(d1, 1);
        d0 += __shfl_xor(d0, 2); d1 += __shfl_xor(d1, 2);
        d0 += __shfl_xor(d0, 4); d1 += __shfl_xor(d1, 4);
        float e0 = v0 ? __expf(fmaxf(d0 * 0.125f, 0.f)) : 0.f;
        float e1 = v1 ? __expf(fmaxf(d1 * 0.125f, 0.f)) : 0.f;
        s += e0 + e1;
        if (v0 && li == 0) ecsr[start + idx0] = e0;
        if (v1 && li == 0) ecsr[start + idx1] = e1;
        __half2 e20 = __float2half2_rn(e0);
        __half2 e21 = __float2half2_rn(e1);
        #pragma unroll
        for (int j = 0; j < 4; ++j) {
            acc2[j] = __hfma2(e20, V0.h[j], acc2[j]);
            acc2[j] = __hfma2(e21, V1.h[j], acc2[j]);
        }
    }
    // combine the 8 groups
    #pragma unroll
    for (int off = 8; off < 64; off <<= 1) {
        s += __shfl_xor(s, off);
        #pragma unroll
        for (int j = 0; j < 4; ++j)
            acc2[j] = __hadd2(acc2[j], shfl_xor_h2(acc2[j], off));
    }
    float inv = 1.0f / (s + 1e-16f);
    if (lane == 0) dnode[node] = inv;
    float af[8];
    #pragma unroll
    for (int j = 0; j < 4; ++j) {
        af[2 * j]     = __low2float(acc2[j]);
        af[2 * j + 1] = __high2float(acc2[j]);
    }

    if (!LAST) {
        if (g == 0) {
            float4 o0, o1;
            o0.x = af[0] * inv; o0.y = af[1] * inv; o0.z = af[2] * inv; o0.w = af[3] * inv;
            o1.x = af[4] * inv; o1.y = af[5] * inv; o1.z = af[6] * inv; o1.w = af[7] * inv;
            *reinterpret_cast<float4*>(hout + (size_t)node * HH + li * 8)     = o0;
            *reinterpret_cast<float4*>(hout + (size_t)node * HH + li * 8 + 4) = o1;
        }
    } else {
        float4 w0 = *reinterpret_cast<const float4*>(Wsig + li * 8);
        float4 w1 = *reinterpret_cast<const float4*>(Wsig + li * 8 + 4);
        float t = af[0] * w0.x + af[1] * w0.y + af[2] * w0.z + af[3] * w0.w
                + af[4] * w1.x + af[5] * w1.y + af[6] * w1.z + af[7] * w1.w;
        t *= inv;
        t += __shfl_xor(t, 1);
        t += __shfl_xor(t, 2);
        t += __shfl_xor(t, 4);
        if (lane == 0) signals[node] = t + bsig[0];
    }
}

// ---------------- fused dispatches (parity-interleaved block split) ----------------
__global__ __launch_bounds__(256) void k_proj_partB3(
        const float* __restrict__ x, const short* __restrict__ wf,
        const float* __restrict__ b, float* __restrict__ h, int n,
        const int* __restrict__ src, const int* __restrict__ dst,
        const int* __restrict__ blockBase, const int* __restrict__ bucketBase,
        ull* __restrict__ bps, int E, int PB, int NB) {
    int bid = blockIdx.x >> 1;
    if ((blockIdx.x & 1) == 0) do_proj(bid, x, wf, b, h, n);
    else                       do_partB3(bid, src, dst, blockBase, bucketBase, bps, E, PB, NB);
}

__global__ __launch_bounds__(256) void k_qkv_partC1(
        const float* __restrict__ hsrc,
        const short* __restrict__ wfq, const short* __restrict__ wfk, const short* __restrict__ wfv,
        __half* __restrict__ qh, __half* __restrict__ kv, int n,
        const ull* __restrict__ bps, const int* __restrict__ bucketBase,
        int* __restrict__ rowptr, int* __restrict__ esrc, int* __restrict__ inv, int NB) {
    int bid = blockIdx.x >> 1;
    if ((blockIdx.x & 1) == 0) do_qkv(bid, hsrc, wfq, wfk, wfv, qh, kv, n);
    else                       do_partC1(bid, bps, bucketBase, rowptr, esrc, inv, n, NB);
}

__global__ __launch_bounds__(256) void k_qkv_attn(
        const float* __restrict__ hsrc,
        const short* __restrict__ wfq, const short* __restrict__ wfk, const short* __restrict__ wfv,
        __half* __restrict__ qh, __half* __restrict__ kv, int n,
        const float* __restrict__ ecsr, const int* __restrict__ inv,
        const float* __restrict__ dnode, const int* __restrict__ dst,
        float* __restrict__ attn, int E) {
    int bid = blockIdx.x >> 1;
    if ((blockIdx.x & 1) == 0) do_qkv(bid, hsrc, wfq, wfk, wfv, qh, kv, n);
    else                       do_attn(bid, ecsr, inv, dnode, dst, attn, E);
}

__global__ __launch_bounds__(256) void k_attn(const float* __restrict__ ecsr,
        const int* __restrict__ inv, const float* __restrict__ dnode,
        const int* __restrict__ dst, float* __restrict__ attn, int E) {
    do_attn(blockIdx.x, ecsr, inv, dnode, dst, attn, E);
}

extern "C" void kernel_launch(void* const* d_in, const int* in_sizes, int n_in,
                              void* d_out, int out_size, void* d_ws, size_t ws_size,
                              hipStream_t stream) {
    const float* x   = (const float*)d_in[0];
    const int*   ei  = (const int*)  d_in[1];
    const float* Wp  = (const float*)d_in[2];
    const float* bp  = (const float*)d_in[3];
    const float* Wq1 = (const float*)d_in[4];
    const float* Wk1 = (const float*)d_in[5];
    const float* Wv1 = (const float*)d_in[6];
    const float* Wq2 = (const float*)d_in[7];
    const float* Wk2 = (const float*)d_in[8];
    const float* Wv2 = (const float*)d_in[9];
    const float* Wsg = (const float*)d_in[10];
    const float* bsg = (const float*)d_in[11];

    const int N = in_sizes[0] / FF;
    const int E = in_sizes[1] / 2;
    const int* src = ei;
    const int* dst = ei + E;

    const int NB = (N + 511) >> 9;       // buckets of 512 nodes (needs NB <= 256)
    const int PB = (E + 4095) >> 12;     // partition blocks of 4096 edges (needs PB <= 512)

    char* ws = (char*)d_ws;
    size_t off = 0;
    auto alloc = [&](size_t bytes) -> void* {
        void* p = ws + off;
        off += (bytes + 255) & ~(size_t)255;
        return p;
    };
    __half* qh   = (__half*)alloc((size_t)N * HH * 2);
    __half* kv   = (__half*)alloc((size_t)N * 128 * 2);
    float* h     = (float*)alloc((size_t)N * HH * 4);
    float* ecsr  = (float*)alloc((size_t)E * 4);
    int* inv     = (int*)alloc((size_t)E * 4);
    int* esrc    = (int*)alloc((size_t)E * 4);
    float* dnode = (float*)alloc((size_t)N * 4);
    ull* bps     = (ull*)alloc((size_t)E * 8);
    int* rowptr  = (int*)alloc((size_t)(N + 1) * 4);
    int* blockHist   = (int*)alloc((size_t)NB * PB * 4);
    int* bucketTotal = (int*)alloc((size_t)NB * 4);
    int* bucketBase  = (int*)alloc((size_t)(NB + 1) * 4);
    short* wf    = (short*)alloc((size_t)81920 * 2);  // W fragment tables

    float* out     = (float*)d_out;
    float* signals = out;
    float* attn1   = out + N;
    float* attn2   = out + N + E;

    // W fragment prep (independent of everything else)
    k_wprep<<<64, 256, 0, stream>>>(Wp, Wq1, Wk1, Wv1, Wq2, Wk2, Wv2, wf);

    // partition prefix sums (LDS histograms, no global atomics)
    k_partA<<<PB, 256, 0, stream>>>(dst, blockHist, E, PB, NB);
    k_partA2<<<NB, 512, 0, stream>>>(blockHist, bucketTotal, PB);
    k_partA2b<<<1, 256, 0, stream>>>(bucketTotal, bucketBase, rowptr, NB, N, E);

    int gemmBlocks = (N + 63) / 64;              // 1563
    int e4Blocks   = ((E + 3) / 4 + 255) / 256;  // 1563
    int edgeBlocks = (N + 3) / 4;                // 25000

    // proj (MFMA) ∥ partB3 (one 8B store per edge)
    int f1 = 2 * max(gemmBlocks, PB);
    k_proj_partB3<<<f1, 256, 0, stream>>>(x, wf, bp, h, N,
            src, dst, blockHist, bucketBase, bps, E, PB, NB);

    const short* wfbase = wf + 32768;
    // qkv1 (MFMA) ∥ partC1 (per-bucket finalize incl. inv scatter)
    int f2 = 2 * max(gemmBlocks, NB);
    k_qkv_partC1<<<f2, 256, 0, stream>>>(h, wfbase, wfbase + 8192, wfbase + 16384,
            qh, kv, N, bps, bucketBase, rowptr, esrc, inv, NB);

    // edge1 standalone
    k_edge<false><<<edgeBlocks, 256, 0, stream>>>(qh, kv, rowptr, esrc,
            ecsr, dnode, h, nullptr, nullptr, nullptr, N);

    // qkv2 (MFMA) ∥ attn1 (gather + dnode multiply)
    int f4 = 2 * max(gemmBlocks, e4Blocks);
    k_qkv_attn<<<f4, 256, 0, stream>>>(h, wfbase + 24576, wfbase + 32768, wfbase + 40960,
            qh, kv, N, ecsr, inv, dnode, dst, attn1, E);

    // edge2 (+ fused signal head)
    k_edge<true><<<edgeBlocks, 256, 0, stream>>>(qh, kv, rowptr, esrc,
            ecsr, dnode, nullptr, signals, Wsg, bsg, N);
    k_attn<<<e4Blocks, 256, 0, stream>>>(ecsr, inv, dnode, dst, attn2, E);
}

// Round 15
// 304.748 us; speedup vs baseline: 1.0956x; 1.0099x over previous
//
#include <hip/hip_runtime.h>
#include <hip/hip_fp16.h>
#include <math.h>

#define FF 256
#define HH 64

typedef __attribute__((ext_vector_type(8))) short short8;
typedef __attribute__((ext_vector_type(4))) float f32x4;
typedef unsigned long long ull;

// cheap gelu: A&S 7.1.26 erf approximation, |err| <= 1.5e-7
__device__ __forceinline__ float gelu_f(float x) {
    float ax = fabsf(x) * 0.70710678118654752f;
    float t = __builtin_amdgcn_rcpf(fmaf(0.3275911f, ax, 1.0f));
    float poly = t * fmaf(t, fmaf(t, fmaf(t, fmaf(t, 1.061405429f, -1.453152027f),
                  1.421413741f), -0.284496736f), 0.254829592f);
    float er = 1.0f - poly * __expf(-ax * ax);
    er = (x < 0.f) ? -er : er;
    return 0.5f * x * (1.0f + er);
}

__device__ __forceinline__ unsigned short bf16rne(float f) {
    unsigned u = __float_as_uint(f);
    unsigned r = u + 0x7FFFu + ((u >> 16) & 1u);
    return (unsigned short)(r >> 16);
}

// split f into bf16 hi + bf16 lo (RNE)
__device__ __forceinline__ void bf16split(float f, short& hi, short& lo) {
    unsigned u = __float_as_uint(f);
    unsigned r = u + 0x7FFFu + ((u >> 16) & 1u);
    hi = (short)(r >> 16);
    float fh = __uint_as_float(r & 0xFFFF0000u);
    float fl = f - fh;
    unsigned u2 = __float_as_uint(fl);
    unsigned r2 = u2 + 0x7FFFu + ((u2 >> 16) & 1u);
    lo = (short)(r2 >> 16);
}

__device__ __forceinline__ __half2 shfl_xor_h2(__half2 v, int off) {
    union { __half2 h; int i; } u;
    u.h = v;
    u.i = __shfl_xor(u.i, off, 64);
    return u.h;
}

// ---- W fragment tables in workspace (bf16 hi/lo, fragment-ordered) ----
__global__ __launch_bounds__(256) void k_wprep(
        const float* __restrict__ Wp,
        const float* __restrict__ Wq1, const float* __restrict__ Wk1, const float* __restrict__ Wv1,
        const float* __restrict__ Wq2, const float* __restrict__ Wk2, const float* __restrict__ Wv2,
        short* __restrict__ wf) {
    int total = 16384 + 6 * 4096;
    for (int gid = blockIdx.x * 256 + threadIdx.x; gid < total; gid += gridDim.x * 256) {
        const float* W;
        int fid, hibase, lobase;
        if (gid < 16384) {
            W = Wp; fid = gid; hibase = 0; lobase = 16384;
        } else {
            int t = gid - 16384;
            int m = t >> 12;
            fid = t & 4095;
            switch (m) {
                case 0: W = Wq1; break;
                case 1: W = Wk1; break;
                case 2: W = Wv1; break;
                case 3: W = Wq2; break;
                case 4: W = Wk2; break;
                default: W = Wv2; break;
            }
            hibase = 32768 + m * 8192;
            lobase = hibase + 4096;
        }
        int j    = fid & 7;
        int lane = (fid >> 3) & 63;
        int ct   = (fid >> 9) & 3;
        int s    = fid >> 11;
        int k    = s * 32 + (lane >> 4) * 8 + j;
        int col  = ct * 16 + (lane & 15);
        short hi, lo;
        bf16split(W[k * HH + col], hi, lo);
        wf[hibase + fid] = hi;
        wf[lobase + fid] = lo;
    }
}

// ================= radix-partition CSR build v3 (no global atomics) =================
// bucket = dst >> 9 (512 nodes/bucket). pack = (local<<38)|(src<<21)|eid (47 bits).

// Pass A: per-block bucket histogram -> blockHist[bucket*PB + block]
__global__ __launch_bounds__(256) void k_partA(const int* __restrict__ dst,
        int* __restrict__ blockHist, int E, int PB, int NB) {
    __shared__ int hist[256];
    int t = threadIdx.x, bid = blockIdx.x;
    hist[t] = 0;
    __syncthreads();
    int base = bid * 4096;
    int e0 = base + t * 4;
    if (base + 4095 < E) {
        #pragma unroll
        for (int i = 0; i < 4; ++i) {
            int4 d = *reinterpret_cast<const int4*>(dst + e0 + i * 1024);
            atomicAdd(&hist[d.x >> 9], 1);
            atomicAdd(&hist[d.y >> 9], 1);
            atomicAdd(&hist[d.z >> 9], 1);
            atomicAdd(&hist[d.w >> 9], 1);
        }
    } else {
        for (int i = 0; i < 4; ++i)
            for (int j = 0; j < 4; ++j) {
                int e = e0 + i * 1024 + j;
                if (e < E) atomicAdd(&hist[dst[e] >> 9], 1);
            }
    }
    __syncthreads();
    if (t < NB) blockHist[t * PB + bid] = hist[t];
}

// Pass A2: per-bucket exclusive scan over blocks (in place); total -> bucketTotal
__global__ __launch_bounds__(512) void k_partA2(int* __restrict__ blockHist,
        int* __restrict__ bucketTotal, int PB) {
    __shared__ int buf[512];
    int t = threadIdx.x, b = blockIdx.x;
    int orig = (t < PB) ? blockHist[b * PB + t] : 0;
    buf[t] = orig;
    __syncthreads();
    #pragma unroll
    for (int off = 1; off < 512; off <<= 1) {
        int v = (t >= off) ? buf[t - off] : 0;
        __syncthreads();
        buf[t] += v;
        __syncthreads();
    }
    if (t < PB) blockHist[b * PB + t] = buf[t] - orig;
    if (t == 511) bucketTotal[b] = buf[511];
}

// Pass A2b: scan bucket totals -> bucketBase[NB+1]; also rowptr[N] = E
__global__ __launch_bounds__(256) void k_partA2b(const int* __restrict__ bucketTotal,
        int* __restrict__ bucketBase, int* __restrict__ rowptr, int NB, int N, int E) {
    __shared__ int buf[256];
    int t = threadIdx.x;
    int orig = (t < NB) ? bucketTotal[t] : 0;
    buf[t] = orig;
    __syncthreads();
    #pragma unroll
    for (int off = 1; off < 256; off <<= 1) {
        int v = (t >= off) ? buf[t - off] : 0;
        __syncthreads();
        buf[t] += v;
        __syncthreads();
    }
    if (t < NB) bucketBase[t] = buf[t] - orig;
    if (t == 0) { bucketBase[NB] = buf[255]; rowptr[N] = E; }
}

// Pass B3: scatter packed edges into bucket-partitioned bps64 (one 8B store/edge).
__device__ __forceinline__ void do_partB3(int bid, const int* __restrict__ src,
        const int* __restrict__ dst, const int* __restrict__ blockBase,
        const int* __restrict__ bucketBase,
        ull* __restrict__ bps, int E, int PB, int NB) {
    if (bid >= PB) return;
    __shared__ int cur[256];
    int t = threadIdx.x;
    if (t < NB) cur[t] = bucketBase[t] + blockBase[t * PB + bid];
    __syncthreads();
    int base = bid * 4096;
    int e0 = base + t * 4;
    auto place = [&](int d, int s, int e) {
        int bu = d >> 9;
        int pos = atomicAdd(&cur[bu], 1);
        bps[pos] = ((ull)(d & 511) << 38) | ((ull)s << 21) | (unsigned)e;
    };
    if (base + 4095 < E) {
        #pragma unroll
        for (int i = 0; i < 4; ++i) {
            int4 d4 = *reinterpret_cast<const int4*>(dst + e0 + i * 1024);
            int4 s4 = *reinterpret_cast<const int4*>(src + e0 + i * 1024);
            int eb = e0 + i * 1024;
            place(d4.x, s4.x, eb);
            place(d4.y, s4.y, eb + 1);
            place(d4.z, s4.z, eb + 2);
            place(d4.w, s4.w, eb + 3);
        }
    } else {
        for (int i = 0; i < 4; ++i)
            for (int j = 0; j < 4; ++j) {
                int e = e0 + i * 1024 + j;
                if (e < E) place(dst[e], src[e], e);
            }
    }
}

// Pass C1: per-bucket CSR finalize. Writes rowptr, esrc (bucket-local), inv (scatter).
__device__ __forceinline__ void do_partC1(int b, const ull* __restrict__ bps,
        const int* __restrict__ bucketBase,
        int* __restrict__ rowptr, int* __restrict__ esrc, int* __restrict__ inv,
        int N, int NB) {
    if (b >= NB) return;
    __shared__ int cnt[512], sc[512], cur[512], pairbuf[256];
    int t = threadIdx.x;
    cnt[t] = 0; cnt[t + 256] = 0;
    cur[t] = 0; cur[t + 256] = 0;
    __syncthreads();
    int rB = bucketBase[b], rE = bucketBase[b + 1];
    for (int p = rB + t; p < rE; p += 256)
        atomicAdd(&cnt[(int)(bps[p] >> 38)], 1);
    __syncthreads();
    int a  = cnt[2 * t], b2 = cnt[2 * t + 1];
    int ps = a + b2;
    pairbuf[t] = ps;
    __syncthreads();
    #pragma unroll
    for (int off = 1; off < 256; off <<= 1) {
        int v = (t >= off) ? pairbuf[t - off] : 0;
        __syncthreads();
        pairbuf[t] += v;
        __syncthreads();
    }
    int pex = pairbuf[t] - ps;
    sc[2 * t]     = pex;
    sc[2 * t + 1] = pex + a;
    __syncthreads();
    int lo = b << 9;
    #pragma unroll
    for (int i = 0; i < 2; ++i) {
        int idx = t + i * 256;
        int node = lo + idx;
        if (node < N) rowptr[node] = rB + sc[idx];
    }
    for (int p = rB + t; p < rE; p += 256) {
        ull u = bps[p];
        int local = (int)(u >> 38);
        int s = (int)((u >> 21) & 0x1FFFF);
        int r = atomicAdd(&cur[local], 1);
        int pos = rB + sc[local] + r;
        esrc[pos] = s;
        inv[(int)(u & 0x1FFFFF)] = pos;
    }
}

// edge-order attention: attn[e] = ecsr_unnorm[inv[e]] * dnode[dst[e]]
__device__ __forceinline__ void do_attn(int bid, const float* __restrict__ ecsr,
        const int* __restrict__ inv, const float* __restrict__ dnode,
        const int* __restrict__ dst, float* __restrict__ attn, int E) {
    int e0 = (bid * 256 + threadIdx.x) * 4;
    if (e0 + 3 < E) {
        int4 i4 = *reinterpret_cast<const int4*>(inv + e0);
        int4 d4 = *reinterpret_cast<const int4*>(dst + e0);
        float4 a;
        a.x = ecsr[i4.x] * dnode[d4.x];
        a.y = ecsr[i4.y] * dnode[d4.y];
        a.z = ecsr[i4.z] * dnode[d4.z];
        a.w = ecsr[i4.w] * dnode[d4.w];
        *reinterpret_cast<float4*>(attn + e0) = a;
    } else {
        for (int e = e0; e < E; ++e) attn[e] = ecsr[inv[e]] * dnode[dst[e]];
    }
}

__device__ __forceinline__ void do_proj(int bid, const float* __restrict__ x,
        const short* __restrict__ wf, const float* __restrict__ b,
        float* __restrict__ h, int n) {
    if (bid * 64 >= n) return;
    int lane = threadIdx.x & 63;
    int w    = threadIdx.x >> 6;
    int m    = lane & 15, g = lane >> 4;
    int rowc = min(bid * 64 + w * 16 + m, n - 1);
    const float* xrow = x + (size_t)rowc * FF + g * 8;
    const short* wlo = wf + 16384;
    f32x4 acc[4];
    #pragma unroll
    for (int ct = 0; ct < 4; ++ct) acc[ct] = (f32x4){0.f, 0.f, 0.f, 0.f};
    #pragma unroll
    for (int s = 0; s < 8; ++s) {
        float4 a0 = *reinterpret_cast<const float4*>(xrow + s * 32);
        float4 a1 = *reinterpret_cast<const float4*>(xrow + s * 32 + 4);
        float av[8] = {a0.x, a0.y, a0.z, a0.w, a1.x, a1.y, a1.z, a1.w};
        short8 ah, al;
        #pragma unroll
        for (int j = 0; j < 8; ++j) { short hi, lo; bf16split(av[j], hi, lo); ah[j] = hi; al[j] = lo; }
        #pragma unroll
        for (int ct = 0; ct < 4; ++ct) {
            int fo = ((s * 4 + ct) * 64 + lane) * 8;
            short8 bh = *reinterpret_cast<const short8*>(wf + fo);
            short8 bl = *reinterpret_cast<const short8*>(wlo + fo);
            acc[ct] = __builtin_amdgcn_mfma_f32_16x16x32_bf16(ah, bh, acc[ct], 0, 0, 0);
            acc[ct] = __builtin_amdgcn_mfma_f32_16x16x32_bf16(al, bh, acc[ct], 0, 0, 0);
            acc[ct] = __builtin_amdgcn_mfma_f32_16x16x32_bf16(ah, bl, acc[ct], 0, 0, 0);
        }
    }
    int orow0 = bid * 64 + w * 16 + g * 4;
    #pragma unroll
    for (int ct = 0; ct < 4; ++ct) {
        int col = ct * 16 + m;
        float bias = b[col];
        #pragma unroll
        for (int r = 0; r < 4; ++r) {
            int row = orow0 + r;
            if (row < n) h[(size_t)row * HH + col] = acc[ct][r] + bias;   // raw; gelu in qkv
        }
    }
}

// kv row layout (128 halves): block b=c>>3 : k[c] at b*16+(c&7), v[c] at b*16+8+(c&7)
__device__ __forceinline__ void do_qkv(int bid, const float* __restrict__ hsrc,
        const short* __restrict__ wfq, const short* __restrict__ wfk, const short* __restrict__ wfv,
        __half* __restrict__ qh, __half* __restrict__ kv, int n) {
    if (bid * 64 >= n) return;
    int lane = threadIdx.x & 63;
    int w    = threadIdx.x >> 6;
    int m    = lane & 15, g = lane >> 4;
    int rowc = min(bid * 64 + w * 16 + m, n - 1);
    const float* hrow = hsrc + (size_t)rowc * HH + g * 8;
    f32x4 aq[4], ak[4], av_[4];
    #pragma unroll
    for (int ct = 0; ct < 4; ++ct) {
        aq[ct] = (f32x4){0.f, 0.f, 0.f, 0.f};
        ak[ct] = (f32x4){0.f, 0.f, 0.f, 0.f};
        av_[ct] = (f32x4){0.f, 0.f, 0.f, 0.f};
    }
    #pragma unroll
    for (int s = 0; s < 2; ++s) {
        float4 a0 = *reinterpret_cast<const float4*>(hrow + s * 32);
        float4 a1 = *reinterpret_cast<const float4*>(hrow + s * 32 + 4);
        float avv[8] = {a0.x, a0.y, a0.z, a0.w, a1.x, a1.y, a1.z, a1.w};
        short8 ah;
        #pragma unroll
        for (int j = 0; j < 8; ++j) ah[j] = (short)bf16rne(gelu_f(avv[j]));
        #pragma unroll
        for (int ct = 0; ct < 4; ++ct) {
            int fo = ((s * 4 + ct) * 64 + lane) * 8;
            short8 qh8 = *reinterpret_cast<const short8*>(wfq + fo);
            short8 ql8 = *reinterpret_cast<const short8*>(wfq + 4096 + fo);
            short8 kh8 = *reinterpret_cast<const short8*>(wfk + fo);
            short8 kl8 = *reinterpret_cast<const short8*>(wfk + 4096 + fo);
            short8 vh8 = *reinterpret_cast<const short8*>(wfv + fo);
            short8 vl8 = *reinterpret_cast<const short8*>(wfv + 4096 + fo);
            aq[ct] = __builtin_amdgcn_mfma_f32_16x16x32_bf16(ah, qh8, aq[ct], 0, 0, 0);
            aq[ct] = __builtin_amdgcn_mfma_f32_16x16x32_bf16(ah, ql8, aq[ct], 0, 0, 0);
            ak[ct] = __builtin_amdgcn_mfma_f32_16x16x32_bf16(ah, kh8, ak[ct], 0, 0, 0);
            ak[ct] = __builtin_amdgcn_mfma_f32_16x16x32_bf16(ah, kl8, ak[ct], 0, 0, 0);
            av_[ct] = __builtin_amdgcn_mfma_f32_16x16x32_bf16(ah, vh8, av_[ct], 0, 0, 0);
            av_[ct] = __builtin_amdgcn_mfma_f32_16x16x32_bf16(ah, vl8, av_[ct], 0, 0, 0);
        }
    }
    int orow0 = bid * 64 + w * 16 + g * 4;
    #pragma unroll
    for (int ct = 0; ct < 4; ++ct) {
        int col = ct * 16 + m;
        int cb  = (col >> 3) * 16 + (col & 7);
        #pragma unroll
        for (int r = 0; r < 4; ++r) {
            int row = orow0 + r;
            if (row < n) {
                qh[(size_t)row * HH + col]     = __float2half(aq[ct][r]);
                kv[(size_t)row * 128 + cb]     = __float2half(ak[ct][r]);
                kv[(size_t)row * 128 + cb + 8] = __float2half(av_[ct][r]);
            }
        }
    }
}

// ---------------- edge phase: one wave/node, 8 lanes/edge; unnormalized ecsr + dnode --
template<bool LAST>
__global__ __launch_bounds__(256) void k_edge(
        const __half* __restrict__ qarr, const __half* __restrict__ kv,
        const int* __restrict__ rowptr,
        const int* __restrict__ esrc,
        float* __restrict__ ecsr,
        float* __restrict__ dnode,
        float* __restrict__ hout,
        float* __restrict__ signals,
        const float* __restrict__ Wsig, const float* __restrict__ bsig,
        int n) {
    int node = blockIdx.x * 4 + (threadIdx.x >> 6);
    if (node >= n) return;
    int lane = threadIdx.x & 63;
    int li = lane & 7, g = lane >> 3;
    int start = rowptr[node], end = rowptr[node + 1];
    int deg = end - start;
    __half2 q2[4];
    {
        union { uint4 u; __half2 h[4]; } Q;
        Q.u = *reinterpret_cast<const uint4*>(qarr + (size_t)node * HH + li * 8);
        #pragma unroll
        for (int j = 0; j < 4; ++j) q2[j] = Q.h[j];
    }
    int p0 = start + lane;
    int el = (p0 < end) ? esrc[p0] : 0;   // first 64 source indices in registers

    __half2 acc2[4];
    #pragma unroll
    for (int j = 0; j < 4; ++j) acc2[j] = __float2half2_rn(0.f);
    float s = 0.f;
    for (int c = 0; c < deg; c += 16) {
        int idx0 = c + g, idx1 = c + 8 + g;
        bool v0 = idx0 < deg, v1 = idx1 < deg;
        int sv0, sv1;
        if (c + 16 <= 64) {
            sv0 = __shfl(el, idx0);
            sv1 = __shfl(el, idx1);
        } else {
            sv0 = v0 ? esrc[start + idx0] : 0;
            sv1 = v1 ? esrc[start + idx1] : 0;
        }
        const __half* b0 = kv + (size_t)sv0 * 128 + li * 16;
        const __half* b1 = kv + (size_t)sv1 * 128 + li * 16;
        union { uint4 u; __half2 h[4]; } K0, V0, K1, V1;
        K0.u = *reinterpret_cast<const uint4*>(b0);
        V0.u = *reinterpret_cast<const uint4*>(b0 + 8);
        K1.u = *reinterpret_cast<const uint4*>(b1);
        V1.u = *reinterpret_cast<const uint4*>(b1 + 8);
        __half2 d20 = __float2half2_rn(0.f);
        __half2 d21 = __float2half2_rn(0.f);
        #pragma unroll
        for (int j = 0; j < 4; ++j) {
            d20 = __hfma2(q2[j], K0.h[j], d20);
            d21 = __hfma2(q2[j], K1.h[j], d21);
        }
        float d0 = __low2float(d20) + __high2float(d20);
        float d1 = __low2float(d21) + __high2float(d21);
        d0 += __shfl_xor(d0, 1); d1 += __shfl_xor(d1, 1);
        d0 += __shfl_xor(d0, 2); d1 += __shfl_xor(d1, 2);
        d0 += __shfl_xor(d0, 4); d1 += __shfl_xor(d1, 4);
        float e0 = v0 ? __expf(fmaxf(d0 * 0.125f, 0.f)) : 0.f;
        float e1 = v1 ? __expf(fmaxf(d1 * 0.125f, 0.f)) : 0.f;
        s += e0 + e1;
        if (v0 && li == 0) ecsr[start + idx0] = e0;
        if (v1 && li == 0) ecsr[start + idx1] = e1;
        __half2 e20 = __float2half2_rn(e0);
        __half2 e21 = __float2half2_rn(e1);
        #pragma unroll
        for (int j = 0; j < 4; ++j) {
            acc2[j] = __hfma2(e20, V0.h[j], acc2[j]);
            acc2[j] = __hfma2(e21, V1.h[j], acc2[j]);
        }
    }
    // combine the 8 groups
    #pragma unroll
    for (int off = 8; off < 64; off <<= 1) {
        s += __shfl_xor(s, off);
        #pragma unroll
        for (int j = 0; j < 4; ++j)
            acc2[j] = __hadd2(acc2[j], shfl_xor_h2(acc2[j], off));
    }
    float inv = 1.0f / (s + 1e-16f);
    if (lane == 0) dnode[node] = inv;
    float af[8];
    #pragma unroll
    for (int j = 0; j < 4; ++j) {
        af[2 * j]     = __low2float(acc2[j]);
        af[2 * j + 1] = __high2float(acc2[j]);
    }

    if (!LAST) {
        if (g == 0) {
            float4 o0, o1;
            o0.x = af[0] * inv; o0.y = af[1] * inv; o0.z = af[2] * inv; o0.w = af[3] * inv;
            o1.x = af[4] * inv; o1.y = af[5] * inv; o1.z = af[6] * inv; o1.w = af[7] * inv;
            *reinterpret_cast<float4*>(hout + (size_t)node * HH + li * 8)     = o0;
            *reinterpret_cast<float4*>(hout + (size_t)node * HH + li * 8 + 4) = o1;
        }
    } else {
        float4 w0 = *reinterpret_cast<const float4*>(Wsig + li * 8);
        float4 w1 = *reinterpret_cast<const float4*>(Wsig + li * 8 + 4);
        float t = af[0] * w0.x + af[1] * w0.y + af[2] * w0.z + af[3] * w0.w
                + af[4] * w1.x + af[5] * w1.y + af[6] * w1.z + af[7] * w1.w;
        t *= inv;
        t += __shfl_xor(t, 1);
        t += __shfl_xor(t, 2);
        t += __shfl_xor(t, 4);
        if (lane == 0) signals[node] = t + bsig[0];
    }
}

// -------- fused dispatches: role = bit 3 (rounds of 8 -> both roles on every XCD) ----
__device__ __forceinline__ void role_split(int& role, int& sub) {
    role = (blockIdx.x >> 3) & 1;
    sub  = ((blockIdx.x >> 4) << 3) | (blockIdx.x & 7);
}

__global__ __launch_bounds__(256) void k_proj_partB3(
        const float* __restrict__ x, const short* __restrict__ wf,
        const float* __restrict__ b, float* __restrict__ h, int n,
        const int* __restrict__ src, const int* __restrict__ dst,
        const int* __restrict__ blockBase, const int* __restrict__ bucketBase,
        ull* __restrict__ bps, int E, int PB, int NB) {
    int role, sub;
    role_split(role, sub);
    if (role == 0) do_proj(sub, x, wf, b, h, n);
    else           do_partB3(sub, src, dst, blockBase, bucketBase, bps, E, PB, NB);
}

__global__ __launch_bounds__(256) void k_qkv_partC1(
        const float* __restrict__ hsrc,
        const short* __restrict__ wfq, const short* __restrict__ wfk, const short* __restrict__ wfv,
        __half* __restrict__ qh, __half* __restrict__ kv, int n,
        const ull* __restrict__ bps, const int* __restrict__ bucketBase,
        int* __restrict__ rowptr, int* __restrict__ esrc, int* __restrict__ inv, int NB) {
    int role, sub;
    role_split(role, sub);
    if (role == 0) do_qkv(sub, hsrc, wfq, wfk, wfv, qh, kv, n);
    else           do_partC1(sub, bps, bucketBase, rowptr, esrc, inv, n, NB);
}

__global__ __launch_bounds__(256) void k_qkv_attn(
        const float* __restrict__ hsrc,
        const short* __restrict__ wfq, const short* __restrict__ wfk, const short* __restrict__ wfv,
        __half* __restrict__ qh, __half* __restrict__ kv, int n,
        const float* __restrict__ ecsr, const int* __restrict__ inv,
        const float* __restrict__ dnode, const int* __restrict__ dst,
        float* __restrict__ attn, int E) {
    int role, sub;
    role_split(role, sub);
    if (role == 0) do_qkv(sub, hsrc, wfq, wfk, wfv, qh, kv, n);
    else           do_attn(sub, ecsr, inv, dnode, dst, attn, E);
}

__global__ __launch_bounds__(256) void k_attn(const float* __restrict__ ecsr,
        const int* __restrict__ inv, const float* __restrict__ dnode,
        const int* __restrict__ dst, float* __restrict__ attn, int E) {
    do_attn(blockIdx.x, ecsr, inv, dnode, dst, attn, E);
}

extern "C" void kernel_launch(void* const* d_in, const int* in_sizes, int n_in,
                              void* d_out, int out_size, void* d_ws, size_t ws_size,
                              hipStream_t stream) {
    const float* x   = (const float*)d_in[0];
    const int*   ei  = (const int*)  d_in[1];
    const float* Wp  = (const float*)d_in[2];
    const float* bp  = (const float*)d_in[3];
    const float* Wq1 = (const float*)d_in[4];
    const float* Wk1 = (const float*)d_in[5];
    const float* Wv1 = (const float*)d_in[6];
    const float* Wq2 = (const float*)d_in[7];
    const float* Wk2 = (const float*)d_in[8];
    const float* Wv2 = (const float*)d_in[9];
    const float* Wsg = (const float*)d_in[10];
    const float* bsg = (const float*)d_in[11];

    const int N = in_sizes[0] / FF;
    const int E = in_sizes[1] / 2;
    const int* src = ei;
    const int* dst = ei + E;

    const int NB = (N + 511) >> 9;       // buckets of 512 nodes (needs NB <= 256)
    const int PB = (E + 4095) >> 12;     // partition blocks of 4096 edges (needs PB <= 512)

    char* ws = (char*)d_ws;
    size_t off = 0;
    auto alloc = [&](size_t bytes) -> void* {
        void* p = ws + off;
        off += (bytes + 255) & ~(size_t)255;
        return p;
    };
    __half* qh   = (__half*)alloc((size_t)N * HH * 2);
    __half* kv   = (__half*)alloc((size_t)N * 128 * 2);
    float* h     = (float*)alloc((size_t)N * HH * 4);
    float* ecsr  = (float*)alloc((size_t)E * 4);
    int* inv     = (int*)alloc((size_t)E * 4);
    int* esrc    = (int*)alloc((size_t)E * 4);
    float* dnode = (float*)alloc((size_t)N * 4);
    ull* bps     = (ull*)alloc((size_t)E * 8);
    int* rowptr  = (int*)alloc((size_t)(N + 1) * 4);
    int* blockHist   = (int*)alloc((size_t)NB * PB * 4);
    int* bucketTotal = (int*)alloc((size_t)NB * 4);
    int* bucketBase  = (int*)alloc((size_t)(NB + 1) * 4);
    short* wf    = (short*)alloc((size_t)81920 * 2);  // W fragment tables

    float* out     = (float*)d_out;
    float* signals = out;
    float* attn1   = out + N;
    float* attn2   = out + N + E;

    // W fragment prep (independent of everything else)
    k_wprep<<<64, 256, 0, stream>>>(Wp, Wq1, Wk1, Wv1, Wq2, Wk2, Wv2, wf);

    // partition prefix sums (LDS histograms, no global atomics)
    k_partA<<<PB, 256, 0, stream>>>(dst, blockHist, E, PB, NB);
    k_partA2<<<NB, 512, 0, stream>>>(blockHist, bucketTotal, PB);
    k_partA2b<<<1, 256, 0, stream>>>(bucketTotal, bucketBase, rowptr, NB, N, E);

    int gemmBlocks = (N + 63) / 64;              // 1563
    int e4Blocks   = ((E + 3) / 4 + 255) / 256;  // 1563
    int edgeBlocks = (N + 3) / 4;                // 25000

    // proj (MFMA) ∥ partB3 (one 8B store per edge)
    int f1 = 2 * ((max(gemmBlocks, PB) + 7) & ~7);
    k_proj_partB3<<<f1, 256, 0, stream>>>(x, wf, bp, h, N,
            src, dst, blockHist, bucketBase, bps, E, PB, NB);

    const short* wfbase = wf + 32768;
    // qkv1 (MFMA) ∥ partC1 (per-bucket finalize incl. inv scatter)
    int f2 = 2 * ((max(gemmBlocks, NB) + 7) & ~7);
    k_qkv_partC1<<<f2, 256, 0, stream>>>(h, wfbase, wfbase + 8192, wfbase + 16384,
            qh, kv, N, bps, bucketBase, rowptr, esrc, inv, NB);

    // edge1 standalone
    k_edge<false><<<edgeBlocks, 256, 0, stream>>>(qh, kv, rowptr, esrc,
            ecsr, dnode, h, nullptr, nullptr, nullptr, N);

    // qkv2 (MFMA) ∥ attn1 (gather + dnode multiply)
    int f4 = 2 * ((max(gemmBlocks, e4Blocks) + 7) & ~7);
    k_qkv_attn<<<f4, 256, 0, stream>>>(h, wfbase + 24576, wfbase + 32768, wfbase + 40960,
            qh, kv, N, ecsr, inv, dnode, dst, attn1, E);

    // edge2 (+ fused signal head)
    k_edge<true><<<edgeBlocks, 256, 0, stream>>>(qh, kv, rowptr, esrc,
            ecsr, dnode, nullptr, signals, Wsg, bsg, N);
    k_attn<<<e4Blocks, 256, 0, stream>>>(ecsr, inv, dnode, dst, attn2, E);
}